// Round 23
// baseline (94.257 us; speedup 1.0000x reference)
//
#include <hip/hip_runtime.h>
#include <hip/hip_bf16.h>
#include <cstdint>

// ---------------------------------------------------------------------------
// Fused causal self-attention block (B=2, T=2048, C=1024, H=16, Dh=64), fp32 in/out.
// cvt fp32->bf16 -> QKV GEMM (Q pre-scaled, V written transposed) -> flash attn -> out GEMM.
// Workspace (48MB):
//   yb    @ 0     8 MB   bf16 x (xb) -> DEAD after gemm1 -> reused as yb
//   wqkvb @ 8 MB  6 MB   bf16 w_qkv [3072][1024]
//   wob   @ 14MB  2 MB   bf16 w_out [1024][1024]
//   qkvb  @ 16MB 24 MB   bf16 qkv [4096][3072] (Q scaled | K | V-region unused)
//   vt    @ 40MB  8 MB   bf16 Vt [32 bh][64 d][2048 t] (written by gemm1 epilogue)
// ---------------------------------------------------------------------------

typedef __bf16 bf16x8 __attribute__((ext_vector_type(8)));
typedef float  f32x4  __attribute__((ext_vector_type(4)));
typedef unsigned short u16x4 __attribute__((ext_vector_type(4)));
typedef unsigned int   u32x4 __attribute__((ext_vector_type(4)));

#define EMB   1024
#define HEADS 16
#define HD    64
#define TT    2048
#define NROWS 4096
#define QKVN  3072
#define SCL   0.18033688f   /* 0.125 * log2(e): folded into Q at gemm1 epilogue */
#define THR   11.0f         /* defer-max threshold, log2 units */

// ---- fused fp32 -> bf16 (8 elems / thread, 3 arrays in one launch) ----
__global__ void cvt_all(const float* __restrict__ x, const float* __restrict__ wq,
                        const float* __restrict__ wo, __bf16* __restrict__ xb,
                        __bf16* __restrict__ wqb, __bf16* __restrict__ wob) {
  const int bid = blockIdx.x;
  const float* in; __bf16* out; int i;
  if (bid < 2048)      { in = x;  out = xb;  i = bid * 256 + threadIdx.x; }
  else if (bid < 3584) { in = wq; out = wqb; i = (bid - 2048) * 256 + threadIdx.x; }
  else                 { in = wo; out = wob; i = (bid - 3584) * 256 + threadIdx.x; }
  const float4* p = (const float4*)in + (size_t)i * 2;
  float4 a = p[0], b = p[1];
  bf16x8 o;
  o[0] = (__bf16)a.x; o[1] = (__bf16)a.y; o[2] = (__bf16)a.z; o[3] = (__bf16)a.w;
  o[4] = (__bf16)b.x; o[5] = (__bf16)b.y; o[6] = (__bf16)b.z; o[7] = (__bf16)b.w;
  *((bf16x8*)out + i) = o;
}

__device__ __forceinline__ void gload_lds16(const void* g, void* l) {
  __builtin_amdgcn_global_load_lds(
      (const __attribute__((address_space(1))) void*)(uintptr_t)g,
      (__attribute__((address_space(3))) void*)(uint32_t)(uintptr_t)l,
      16, 0, 0);
}

// ---------------------------------------------------------------------------
// GEMM v3: 128x128 tile, BK=128 (256B LDS rows, 16 chunks) -> 8 barrier
// drains per K=1024 (was 16), 64 MFMA per barrier.  Swizzle sc=pos^(row&15)
// (bijective/row; fragment reads 16 distinct chunks -> <=2-way, free).
// Two half-steps per staging keep fragment register shape identical to BK=64.
// LDS 64KB -> 2 blocks/CU (proven perf-neutral vs 3, R22).  XCD swizzle.
// MODE 1 epilogue: Q scaled, K plain, V transposed to vt.
// ---------------------------------------------------------------------------
template <int MODE>
__global__ __launch_bounds__(256, 2)
void gemm_bt(const __bf16* __restrict__ A, const __bf16* __restrict__ Bm,
             void* __restrict__ Cout, __bf16* __restrict__ vt,
             int M, int N, int K) {
  __shared__ __align__(16) char As[128 * 256];
  __shared__ __align__(16) char Bs[128 * 256];
  const int tid  = threadIdx.x;
  const int lane = tid & 63;
  const int wid  = tid >> 6;
  const int wr = wid >> 1, wc = wid & 1;
  const int nwg = gridDim.x * gridDim.y;
  int flat = blockIdx.y * gridDim.x + blockIdx.x;
  flat = (flat & 7) * (nwg >> 3) + (flat >> 3);
  const int brow = (flat / gridDim.x) * 128;
  const int bcol = (flat % gridDim.x) * 128;
  const int fr = lane & 15, g = lane >> 4;

  f32x4 acc[4][4];
#pragma unroll
  for (int m = 0; m < 4; m++)
#pragma unroll
    for (int n = 0; n < 4; n++)
#pragma unroll
      for (int r = 0; r < 4; r++) acc[m][n][r] = 0.0f;

  for (int k0 = 0; k0 < K; k0 += 128) {
    __syncthreads();
#pragma unroll
    for (int i = 0; i < 8; i++) {                // 2048 chunks per 32KB tile
      const int c = tid + i * 256;
      const int row = c >> 4, pos = c & 15;
      const int sc = pos ^ (row & 15);           // source pre-swizzle, linear dest
      gload_lds16(A  + (size_t)(brow + row) * K + k0 + sc * 8, As + c * 16);
      gload_lds16(Bm + (size_t)(bcol + row) * K + k0 + sc * 8, Bs + c * 16);
    }
    __syncthreads();

#pragma unroll
    for (int half = 0; half < 2; half++) {
      bf16x8 af[4][2], bfr[4][2];
#pragma unroll
      for (int m = 0; m < 4; m++)
#pragma unroll
        for (int kc = 0; kc < 2; kc++) {
          const int row = wr * 64 + m * 16 + fr;
          const int chunk = ((half * 2 + kc) * 4 + g) ^ (row & 15);
          af[m][kc] = *(const bf16x8*)(As + row * 256 + chunk * 16);
        }
#pragma unroll
      for (int n = 0; n < 4; n++)
#pragma unroll
        for (int kc = 0; kc < 2; kc++) {
          const int row = wc * 64 + n * 16 + fr;
          const int chunk = ((half * 2 + kc) * 4 + g) ^ (row & 15);
          bfr[n][kc] = *(const bf16x8*)(Bs + row * 256 + chunk * 16);
        }
#pragma unroll
      for (int kc = 0; kc < 2; kc++)
#pragma unroll
        for (int m = 0; m < 4; m++)
#pragma unroll
          for (int n = 0; n < 4; n++)
            acc[m][n] = __builtin_amdgcn_mfma_f32_16x16x32_bf16(af[m][kc], bfr[n][kc], acc[m][n], 0, 0, 0);
    }
  }

  const int rbase = brow + wr * 64 + g * 4;
  const int cbase = bcol + wc * 64 + fr;
  if (MODE == 0) {
#pragma unroll
    for (int m = 0; m < 4; m++)
#pragma unroll
      for (int n = 0; n < 4; n++) {
        const int col = cbase + n * 16;
#pragma unroll
        for (int r = 0; r < 4; r++)
          ((float*)Cout)[(size_t)(rbase + m * 16 + r) * N + col] = acc[m][n][r];
      }
  } else if (bcol < 2 * EMB) {
    const float qscale = (bcol < EMB) ? SCL : 1.0f;
#pragma unroll
    for (int m = 0; m < 4; m++)
#pragma unroll
      for (int n = 0; n < 4; n++) {
        const int col = cbase + n * 16;
#pragma unroll
        for (int r = 0; r < 4; r++)
          ((__bf16*)Cout)[(size_t)(rbase + m * 16 + r) * N + col] = (__bf16)(acc[m][n][r] * qscale);
      }
  } else {
#pragma unroll
    for (int m = 0; m < 4; m++) {
      const int row0 = rbase + m * 16;
      const int b = row0 >> 11, t0 = row0 & 2047;
#pragma unroll
      for (int n = 0; n < 4; n++) {
        const int vcol = cbase + n * 16 - 2 * EMB;
        const int bh = b * HEADS + (vcol >> 6);
        const int d  = vcol & 63;
        u16x4 pk;
#pragma unroll
        for (int r = 0; r < 4; r++) {
          const __bf16 h = (__bf16)acc[m][n][r];
          pk[r] = *(const unsigned short*)&h;
        }
        *(u16x4*)(vt + ((size_t)bh * HD + d) * TT + t0) = pk;
      }
    }
  }
}

// ---------------------------------------------------------------------------
// Causal flash attention v20 (R21 winner, FROZEN): swapped QK^T, VALU-pipe
// softmax (permlane swaps + cvt_pk), ones-MFMA row-sum on the B-side,
// 3-deep K/V buffers, 3 blocks/CU, LPT, final-iter barrier skip.
// ---------------------------------------------------------------------------
__device__ __forceinline__ int psw(int row) {
  return (((row & 7) ^ ((row >> 3) & 7))) << 4;
}

__device__ __forceinline__ unsigned int pack_bf16(float a, float b) {
  unsigned int r;
  asm("v_cvt_pk_bf16_f32 %0, %1, %2" : "=v"(r) : "v"(a), "v"(b));
  return r;                                      // lo = bf16(a), hi = bf16(b)
}

__device__ __forceinline__ float opaque_f(float x) {
  float y;
  asm volatile("v_mov_b32 %0, %1" : "=v"(y) : "v"(x));
  return y;
}

__global__ __launch_bounds__(256, 3)
void attn_causal20(const __bf16* __restrict__ qkv, const __bf16* __restrict__ vt,
                   __bf16* __restrict__ yb) {
  __shared__ __align__(16) char Kbuf[3][8192];   // K[kv][d], chunk-swizzled
  __shared__ __align__(16) char Vbuf[3][8192];   // Vt[d][kv], chunk-swizzled

  const int tid = threadIdx.x;
  const int lane = tid & 63, w = tid >> 6;
  const int L = blockIdx.x;
  const int bh = L & 31;
  const int chunk = 31 - (L >> 5);               // LPT: longest first
  const int b = bh >> 4, h = bh & 15;
  const size_t rowbase = (size_t)b * TT;
  const int q0 = chunk * 64 + w * 16;
  const int fr = lane & 15, g = lane >> 4;
  const int ntiles = chunk + 1;

  bf16x8 qf[2];
#pragma unroll
  for (int kc = 0; kc < 2; kc++)
    qf[kc] = *(const bf16x8*)(qkv + (rowbase + q0 + fr) * QKVN + h * HD + kc * 32 + g * 8);

  bf16x8 ones;
#pragma unroll
  for (int j = 0; j < 8; j++) ones[j] = (__bf16)1.0f;

  f32x4 o[4];            // O^T frags: lane q=q0+fr holds d = n*16 + g*4 + r
  f32x4 lacc;            // ones-MFMA row-sum: all 4 regs = l_{q=fr}
  float ml = -1e30f;     // running max (scalar per lane)
#pragma unroll
  for (int n = 0; n < 4; n++)
#pragma unroll
    for (int r = 0; r < 4; r++) o[n][r] = 0.0f;
#pragma unroll
  for (int r = 0; r < 4; r++) lacc[r] = 0.0f;

  auto stageKV = [&](int kt, int buf) {
#pragma unroll
    for (int i = 0; i < 2; i++) {
      const int c = tid + i * 256;
      const int row = c >> 3;
      const int c16 = (c & 7) ^ (row & 7);
      gload_lds16(qkv + (rowbase + kt * 64 + row) * QKVN + EMB + h * HD + c16 * 8,
                  Kbuf[buf] + c * 16);
    }
#pragma unroll
    for (int i = 0; i < 2; i++) {
      const int c = tid + i * 256;
      const int row = c >> 3;
      const int c16 = (c & 7) ^ (row & 7);
      gload_lds16(vt + ((size_t)bh * HD + row) * TT + kt * 64 + c16 * 8,
                  Vbuf[buf] + c * 16);
    }
  };

  auto doQK = [&](int kt, f32x4 (&s)[4]) {
    const char* Kc = Kbuf[kt % 3];
    bf16x8 kf[4][2];
#pragma unroll
    for (int n = 0; n < 4; n++)
#pragma unroll
      for (int kc = 0; kc < 2; kc++) {
        const int row = n * 16 + fr;
        kf[n][kc] = *(const bf16x8*)(Kc + row * 128 + (((kc << 2) | g) ^ (row & 7)) * 16);
      }
    __builtin_amdgcn_s_setprio(1);
#pragma unroll
    for (int n = 0; n < 4; n++) {
#pragma unroll
      for (int r = 0; r < 4; r++) s[n][r] = 0.0f;
#pragma unroll
      for (int kc = 0; kc < 2; kc++)
        s[n] = __builtin_amdgcn_mfma_f32_16x16x32_bf16(kf[n][kc], qf[kc], s[n], 0, 0, 0);
    }
    __builtin_amdgcn_s_setprio(0);
  };

  auto doSM = [&](int kt, f32x4 (&s)[4], bf16x8 (&pb)[2]) {
    const int kv0 = kt * 64;
    if (kt == chunk) {                           // causal mask, diagonal tile
      const int qg = q0 + fr;
#pragma unroll
      for (int n = 0; n < 4; n++)
#pragma unroll
        for (int r = 0; r < 4; r++) {
          const int kg = kv0 + n * 16 + g * 4 + r;
          if (kg > qg) s[n][r] = -1e30f;
        }
    }
    float pm = s[0][0];
#pragma unroll
    for (int n = 0; n < 4; n++)
#pragma unroll
      for (int r = 0; r < 4; r++) pm = fmaxf(pm, s[n][r]);
    {
      float c16 = opaque_f(pm);
      asm("v_permlane16_swap_b32 %0, %1" : "+v"(pm), "+v"(c16));
      pm = fmaxf(pm, c16);
      float c32 = opaque_f(pm);
      asm("v_permlane32_swap_b32 %0, %1" : "+v"(pm), "+v"(c32));
      pm = fmaxf(pm, c32);
    }
    if (!__all(pm <= ml + THR)) {
      const float nm = fmaxf(ml, pm);
      const float f = __builtin_amdgcn_exp2f(ml - nm);
      ml = nm;
#pragma unroll
      for (int r = 0; r < 4; r++) lacc[r] *= f;
#pragma unroll
      for (int n = 0; n < 4; n++)
#pragma unroll
        for (int r = 0; r < 4; r++) o[n][r] *= f;
    }
    float p[4][4];
#pragma unroll
    for (int n = 0; n < 4; n++)
#pragma unroll
      for (int r = 0; r < 4; r++)
        p[n][r] = __builtin_amdgcn_exp2f(s[n][r] - ml);
    unsigned int pk[4][2];
#pragma unroll
    for (int n = 0; n < 4; n++)
#pragma unroll
      for (int w2 = 0; w2 < 2; w2++)
        pk[n][w2] = pack_bf16(p[n][2 * w2], p[n][2 * w2 + 1]);
#pragma unroll
    for (int kc = 0; kc < 2; kc++) {
      unsigned int a0 = pk[2 * kc][0], b0 = pk[2 * kc + 1][0];
      asm("v_permlane32_swap_b32 %0, %1" : "+v"(a0), "+v"(b0));
      asm("v_permlane16_swap_b32 %0, %1" : "+v"(a0), "+v"(b0));
      unsigned int a1 = pk[2 * kc][1], b1 = pk[2 * kc + 1][1];
      asm("v_permlane32_swap_b32 %0, %1" : "+v"(a1), "+v"(b1));
      asm("v_permlane16_swap_b32 %0, %1" : "+v"(a1), "+v"(b1));
      u32x4 bw;
      bw[0] = a0; bw[1] = a1; bw[2] = b0; bw[3] = b1;
      pb[kc] = *(bf16x8*)&bw;
    }
  };

  auto doPV = [&](int kt, bf16x8 (&pb)[2]) {
    const char* Vc = Vbuf[kt % 3];
    bf16x8 vb[4][2];
#pragma unroll
    for (int n = 0; n < 4; n++)
#pragma unroll
      for (int kc = 0; kc < 2; kc++) {
        const int row = n * 16 + fr;
        vb[n][kc] = *(const bf16x8*)(Vc + row * 128 + (((kc << 2) | g) ^ (row & 7)) * 16);
      }
    __builtin_amdgcn_s_setprio(1);
#pragma unroll
    for (int kc = 0; kc < 2; kc++) {
      lacc = __builtin_amdgcn_mfma_f32_16x16x32_bf16(ones, pb[kc], lacc, 0, 0, 0);
#pragma unroll
      for (int n = 0; n < 4; n++)
        o[n] = __builtin_amdgcn_mfma_f32_16x16x32_bf16(vb[n][kc], pb[kc], o[n], 0, 0, 0);
    }
    __builtin_amdgcn_s_setprio(0);
  };

  // ---- prologue: stage tiles 0,1; drain; tile-0 QK+SM ----
  stageKV(0, 0);
  if (ntiles > 1) stageKV(1, 1);
  asm volatile("s_waitcnt vmcnt(0)" ::: "memory");
  __builtin_amdgcn_s_barrier();

  bf16x8 pb[2];
  {
    f32x4 s0[4];
    doQK(0, s0);
    doSM(0, s0, pb);
  }

  for (int t = 0; t < ntiles; t++) {
    if (t + 2 < ntiles) stageKV(t + 2, (t + 2) % 3);

    const bool nxt = (t + 1 < ntiles);
    f32x4 s[4];
    if (nxt) doQK(t + 1, s);          // overlaps PV(t)
    doPV(t, pb);                      // consumes pb(t)
    if (nxt) doSM(t + 1, s, pb);      // rescale o AFTER PV(t); makes pb(t+1)

    if (nxt) {                        // final iteration: no drain, no barrier
      asm volatile("s_waitcnt vmcnt(0)" ::: "memory");
      __builtin_amdgcn_s_barrier();
    }
  }

  // ---- epilogue: O^T -> [q][d] via per-wave LDS region (Kbuf dead) ----
  {
    char* Tw = (char*)Kbuf + w * 2048;           // [16 q][64 d] bf16, psw-swizzled
    const float inv = __builtin_amdgcn_rcpf(lacc[0]);
#pragma unroll
    for (int n = 0; n < 4; n++)
#pragma unroll
      for (int r = 0; r < 4; r++) {
        const int d = n * 16 + g * 4 + r;
        *(__bf16*)(Tw + fr * 128 + ((d * 2) ^ psw(fr))) = (__bf16)(o[n][r] * inv);
      }
#pragma unroll
    for (int i = 0; i < 2; i++) {
      const int c = lane + i * 64;               // 128 16B-chunks
      const int row = c >> 3, pos = c & 7;
      const bf16x8 v = *(const bf16x8*)(Tw + row * 128 + ((pos * 16) ^ psw(row)));
      *(bf16x8*)(yb + (rowbase + q0 + row) * EMB + h * HD + pos * 8) = v;
    }
  }
}

extern "C" void kernel_launch(void* const* d_in, const int* in_sizes, int n_in,
                              void* d_out, int out_size, void* d_ws, size_t ws_size,
                              hipStream_t stream) {
  const float* x     = (const float*)d_in[0];
  const float* w_qkv = (const float*)d_in[1];
  const float* w_out = (const float*)d_in[2];
  float* out = (float*)d_out;

  char* ws = (char*)d_ws;
  __bf16* xb    = (__bf16*)(ws);                 // dead after gemm1 -> reused as yb
  __bf16* wqkvb = (__bf16*)(ws + (8ull  << 20));
  __bf16* wob   = (__bf16*)(ws + (14ull << 20));
  __bf16* qkvb  = (__bf16*)(ws + (16ull << 20));
  __bf16* vtb   = (__bf16*)(ws + (40ull << 20));
  __bf16* yb    = xb;

  cvt_all<<<4096, 256, 0, stream>>>(x, w_qkv, w_out, xb, wqkvb, wob);
  gemm_bt<1><<<dim3(QKVN / 128, NROWS / 128), 256, 0, stream>>>(xb, wqkvb, qkvb, vtb, NROWS, QKVN, EMB);
  attn_causal20<<<1024, 256, 0, stream>>>(qkvb, vtb, yb);
  gemm_bt<0><<<dim3(EMB / 128, NROWS / 128), 256, 0, stream>>>(yb, wob, out, nullptr, NROWS, EMB, EMB);
}

// Round 24
// 89.080 us; speedup vs baseline: 1.0581x; 1.0581x over previous
//
#include <hip/hip_runtime.h>
#include <hip/hip_bf16.h>
#include <cstdint>

// ---------------------------------------------------------------------------
// Fused causal self-attention block (B=2, T=2048, C=1024, H=16, Dh=64), fp32 in/out.
// cvt fp32->bf16 -> QKV GEMM (Q pre-scaled, V written transposed) -> flash attn -> out GEMM.
// Workspace (48MB):
//   yb    @ 0     8 MB   bf16 x (xb) -> DEAD after gemm1 -> reused as yb
//   wqkvb @ 8 MB  6 MB   bf16 w_qkv [3072][1024]
//   wob   @ 14MB  2 MB   bf16 w_out [1024][1024]
//   qkvb  @ 16MB 24 MB   bf16 qkv [4096][3072] (Q scaled | K | V-region unused)
//   vt    @ 40MB  8 MB   bf16 Vt [32 bh][64 d][2048 t] (written by gemm1 epilogue)
// ---------------------------------------------------------------------------

typedef __bf16 bf16x8 __attribute__((ext_vector_type(8)));
typedef float  f32x4  __attribute__((ext_vector_type(4)));
typedef unsigned short u16x4 __attribute__((ext_vector_type(4)));
typedef unsigned int   u32x4 __attribute__((ext_vector_type(4)));

#define EMB   1024
#define HEADS 16
#define HD    64
#define TT    2048
#define NROWS 4096
#define QKVN  3072
#define SCL   0.18033688f   /* 0.125 * log2(e): folded into Q at gemm1 epilogue */
#define THR   11.0f         /* defer-max threshold, log2 units */

// ---- fused fp32 -> bf16 (8 elems / thread, 3 arrays in one launch) ----
__global__ void cvt_all(const float* __restrict__ x, const float* __restrict__ wq,
                        const float* __restrict__ wo, __bf16* __restrict__ xb,
                        __bf16* __restrict__ wqb, __bf16* __restrict__ wob) {
  const int bid = blockIdx.x;
  const float* in; __bf16* out; int i;
  if (bid < 2048)      { in = x;  out = xb;  i = bid * 256 + threadIdx.x; }
  else if (bid < 3584) { in = wq; out = wqb; i = (bid - 2048) * 256 + threadIdx.x; }
  else                 { in = wo; out = wob; i = (bid - 3584) * 256 + threadIdx.x; }
  const float4* p = (const float4*)in + (size_t)i * 2;
  float4 a = p[0], b = p[1];
  bf16x8 o;
  o[0] = (__bf16)a.x; o[1] = (__bf16)a.y; o[2] = (__bf16)a.z; o[3] = (__bf16)a.w;
  o[4] = (__bf16)b.x; o[5] = (__bf16)b.y; o[6] = (__bf16)b.z; o[7] = (__bf16)b.w;
  *((bf16x8*)out + i) = o;
}

__device__ __forceinline__ void gload_lds16(const void* g, void* l) {
  __builtin_amdgcn_global_load_lds(
      (const __attribute__((address_space(1))) void*)(uintptr_t)g,
      (__attribute__((address_space(3))) void*)(uint32_t)(uintptr_t)l,
      16, 0, 0);
}

// ---------------------------------------------------------------------------
// GEMM (R22 best): 128x128 tile, BK=64, chunk-swizzled staging, XCD swizzle,
// __launch_bounds__(256,3).  MODE 1: Q scaled, K plain, V transposed to vt.
// ---------------------------------------------------------------------------
template <int MODE>
__global__ __launch_bounds__(256, 3)
void gemm_bt(const __bf16* __restrict__ A, const __bf16* __restrict__ Bm,
             void* __restrict__ Cout, __bf16* __restrict__ vt,
             int M, int N, int K) {
  __shared__ __align__(16) char As[128 * 128];
  __shared__ __align__(16) char Bs[128 * 128];
  const int tid  = threadIdx.x;
  const int lane = tid & 63;
  const int wid  = tid >> 6;
  const int wr = wid >> 1, wc = wid & 1;
  const int nwg = gridDim.x * gridDim.y;
  int flat = blockIdx.y * gridDim.x + blockIdx.x;
  flat = (flat & 7) * (nwg >> 3) + (flat >> 3);
  const int brow = (flat / gridDim.x) * 128;
  const int bcol = (flat % gridDim.x) * 128;
  const int fr = lane & 15, g = lane >> 4;

  f32x4 acc[4][4];
#pragma unroll
  for (int m = 0; m < 4; m++)
#pragma unroll
    for (int n = 0; n < 4; n++)
#pragma unroll
      for (int r = 0; r < 4; r++) acc[m][n][r] = 0.0f;

  for (int k0 = 0; k0 < K; k0 += 64) {
    __syncthreads();
#pragma unroll
    for (int i = 0; i < 4; i++) {
      const int c = tid + i * 256;
      const int row = c >> 3, pos = c & 7;
      const int sc = pos ^ (row & 7);
      gload_lds16(A  + (size_t)(brow + row) * K + k0 + sc * 8, As + c * 16);
      gload_lds16(Bm + (size_t)(bcol + row) * K + k0 + sc * 8, Bs + c * 16);
    }
    __syncthreads();

    bf16x8 af[4][2], bfr[4][2];
#pragma unroll
    for (int m = 0; m < 4; m++)
#pragma unroll
      for (int kc = 0; kc < 2; kc++) {
        const int row = wr * 64 + m * 16 + fr;
        af[m][kc] = *(const bf16x8*)(As + row * 128 + (((kc << 2) | g) ^ (fr & 7)) * 16);
      }
#pragma unroll
    for (int n = 0; n < 4; n++)
#pragma unroll
      for (int kc = 0; kc < 2; kc++) {
        const int row = wc * 64 + n * 16 + fr;
        bfr[n][kc] = *(const bf16x8*)(Bs + row * 128 + (((kc << 2) | g) ^ (fr & 7)) * 16);
      }
#pragma unroll
    for (int kc = 0; kc < 2; kc++)
#pragma unroll
      for (int m = 0; m < 4; m++)
#pragma unroll
        for (int n = 0; n < 4; n++)
          acc[m][n] = __builtin_amdgcn_mfma_f32_16x16x32_bf16(af[m][kc], bfr[n][kc], acc[m][n], 0, 0, 0);
  }

  const int rbase = brow + wr * 64 + g * 4;
  const int cbase = bcol + wc * 64 + fr;
  if (MODE == 0) {
#pragma unroll
    for (int m = 0; m < 4; m++)
#pragma unroll
      for (int n = 0; n < 4; n++) {
        const int col = cbase + n * 16;
#pragma unroll
        for (int r = 0; r < 4; r++)
          ((float*)Cout)[(size_t)(rbase + m * 16 + r) * N + col] = acc[m][n][r];
      }
  } else if (bcol < 2 * EMB) {
    const float qscale = (bcol < EMB) ? SCL : 1.0f;
#pragma unroll
    for (int m = 0; m < 4; m++)
#pragma unroll
      for (int n = 0; n < 4; n++) {
        const int col = cbase + n * 16;
#pragma unroll
        for (int r = 0; r < 4; r++)
          ((__bf16*)Cout)[(size_t)(rbase + m * 16 + r) * N + col] = (__bf16)(acc[m][n][r] * qscale);
      }
  } else {
#pragma unroll
    for (int m = 0; m < 4; m++) {
      const int row0 = rbase + m * 16;
      const int b = row0 >> 11, t0 = row0 & 2047;
#pragma unroll
      for (int n = 0; n < 4; n++) {
        const int vcol = cbase + n * 16 - 2 * EMB;
        const int bh = b * HEADS + (vcol >> 6);
        const int d  = vcol & 63;
        u16x4 pk;
#pragma unroll
        for (int r = 0; r < 4; r++) {
          const __bf16 h = (__bf16)acc[m][n][r];
          pk[r] = *(const unsigned short*)&h;
        }
        *(u16x4*)(vt + ((size_t)bh * HD + d) * TT + t0) = pk;
      }
    }
  }
}

// ---------------------------------------------------------------------------
// Causal flash attention v20 (R21 winner, FROZEN): swapped QK^T, VALU-pipe
// softmax (permlane swaps + cvt_pk), ones-MFMA row-sum on the B-side,
// 3-deep K/V buffers, 3 blocks/CU, LPT, final-iter barrier skip.
// ---------------------------------------------------------------------------
__device__ __forceinline__ int psw(int row) {
  return (((row & 7) ^ ((row >> 3) & 7))) << 4;
}

__device__ __forceinline__ unsigned int pack_bf16(float a, float b) {
  unsigned int r;
  asm("v_cvt_pk_bf16_f32 %0, %1, %2" : "=v"(r) : "v"(a), "v"(b));
  return r;                                      // lo = bf16(a), hi = bf16(b)
}

__device__ __forceinline__ float opaque_f(float x) {
  float y;
  asm volatile("v_mov_b32 %0, %1" : "=v"(y) : "v"(x));
  return y;
}

__global__ __launch_bounds__(256, 3)
void attn_causal20(const __bf16* __restrict__ qkv, const __bf16* __restrict__ vt,
                   __bf16* __restrict__ yb) {
  __shared__ __align__(16) char Kbuf[3][8192];   // K[kv][d], chunk-swizzled
  __shared__ __align__(16) char Vbuf[3][8192];   // Vt[d][kv], chunk-swizzled

  const int tid = threadIdx.x;
  const int lane = tid & 63, w = tid >> 6;
  const int L = blockIdx.x;
  const int bh = L & 31;
  const int chunk = 31 - (L >> 5);               // LPT: longest first
  const int b = bh >> 4, h = bh & 15;
  const size_t rowbase = (size_t)b * TT;
  const int q0 = chunk * 64 + w * 16;
  const int fr = lane & 15, g = lane >> 4;
  const int ntiles = chunk + 1;

  bf16x8 qf[2];
#pragma unroll
  for (int kc = 0; kc < 2; kc++)
    qf[kc] = *(const bf16x8*)(qkv + (rowbase + q0 + fr) * QKVN + h * HD + kc * 32 + g * 8);

  bf16x8 ones;
#pragma unroll
  for (int j = 0; j < 8; j++) ones[j] = (__bf16)1.0f;

  f32x4 o[4];            // O^T frags: lane q=q0+fr holds d = n*16 + g*4 + r
  f32x4 lacc;            // ones-MFMA row-sum: all 4 regs = l_{q=fr}
  float ml = -1e30f;     // running max (scalar per lane)
#pragma unroll
  for (int n = 0; n < 4; n++)
#pragma unroll
    for (int r = 0; r < 4; r++) o[n][r] = 0.0f;
#pragma unroll
  for (int r = 0; r < 4; r++) lacc[r] = 0.0f;

  auto stageKV = [&](int kt, int buf) {
#pragma unroll
    for (int i = 0; i < 2; i++) {
      const int c = tid + i * 256;
      const int row = c >> 3;
      const int c16 = (c & 7) ^ (row & 7);
      gload_lds16(qkv + (rowbase + kt * 64 + row) * QKVN + EMB + h * HD + c16 * 8,
                  Kbuf[buf] + c * 16);
    }
#pragma unroll
    for (int i = 0; i < 2; i++) {
      const int c = tid + i * 256;
      const int row = c >> 3;
      const int c16 = (c & 7) ^ (row & 7);
      gload_lds16(vt + ((size_t)bh * HD + row) * TT + kt * 64 + c16 * 8,
                  Vbuf[buf] + c * 16);
    }
  };

  auto doQK = [&](int kt, f32x4 (&s)[4]) {
    const char* Kc = Kbuf[kt % 3];
    bf16x8 kf[4][2];
#pragma unroll
    for (int n = 0; n < 4; n++)
#pragma unroll
      for (int kc = 0; kc < 2; kc++) {
        const int row = n * 16 + fr;
        kf[n][kc] = *(const bf16x8*)(Kc + row * 128 + (((kc << 2) | g) ^ (row & 7)) * 16);
      }
    __builtin_amdgcn_s_setprio(1);
#pragma unroll
    for (int n = 0; n < 4; n++) {
#pragma unroll
      for (int r = 0; r < 4; r++) s[n][r] = 0.0f;
#pragma unroll
      for (int kc = 0; kc < 2; kc++)
        s[n] = __builtin_amdgcn_mfma_f32_16x16x32_bf16(kf[n][kc], qf[kc], s[n], 0, 0, 0);
    }
    __builtin_amdgcn_s_setprio(0);
  };

  auto doSM = [&](int kt, f32x4 (&s)[4], bf16x8 (&pb)[2]) {
    const int kv0 = kt * 64;
    if (kt == chunk) {                           // causal mask, diagonal tile
      const int qg = q0 + fr;
#pragma unroll
      for (int n = 0; n < 4; n++)
#pragma unroll
        for (int r = 0; r < 4; r++) {
          const int kg = kv0 + n * 16 + g * 4 + r;
          if (kg > qg) s[n][r] = -1e30f;
        }
    }
    float pm = s[0][0];
#pragma unroll
    for (int n = 0; n < 4; n++)
#pragma unroll
      for (int r = 0; r < 4; r++) pm = fmaxf(pm, s[n][r]);
    {
      float c16 = opaque_f(pm);
      asm("v_permlane16_swap_b32 %0, %1" : "+v"(pm), "+v"(c16));
      pm = fmaxf(pm, c16);
      float c32 = opaque_f(pm);
      asm("v_permlane32_swap_b32 %0, %1" : "+v"(pm), "+v"(c32));
      pm = fmaxf(pm, c32);
    }
    if (!__all(pm <= ml + THR)) {
      const float nm = fmaxf(ml, pm);
      const float f = __builtin_amdgcn_exp2f(ml - nm);
      ml = nm;
#pragma unroll
      for (int r = 0; r < 4; r++) lacc[r] *= f;
#pragma unroll
      for (int n = 0; n < 4; n++)
#pragma unroll
        for (int r = 0; r < 4; r++) o[n][r] *= f;
    }
    float p[4][4];
#pragma unroll
    for (int n = 0; n < 4; n++)
#pragma unroll
      for (int r = 0; r < 4; r++)
        p[n][r] = __builtin_amdgcn_exp2f(s[n][r] - ml);
    unsigned int pk[4][2];
#pragma unroll
    for (int n = 0; n < 4; n++)
#pragma unroll
      for (int w2 = 0; w2 < 2; w2++)
        pk[n][w2] = pack_bf16(p[n][2 * w2], p[n][2 * w2 + 1]);
#pragma unroll
    for (int kc = 0; kc < 2; kc++) {
      unsigned int a0 = pk[2 * kc][0], b0 = pk[2 * kc + 1][0];
      asm("v_permlane32_swap_b32 %0, %1" : "+v"(a0), "+v"(b0));
      asm("v_permlane16_swap_b32 %0, %1" : "+v"(a0), "+v"(b0));
      unsigned int a1 = pk[2 * kc][1], b1 = pk[2 * kc + 1][1];
      asm("v_permlane32_swap_b32 %0, %1" : "+v"(a1), "+v"(b1));
      asm("v_permlane16_swap_b32 %0, %1" : "+v"(a1), "+v"(b1));
      u32x4 bw;
      bw[0] = a0; bw[1] = a1; bw[2] = b0; bw[3] = b1;
      pb[kc] = *(bf16x8*)&bw;
    }
  };

  auto doPV = [&](int kt, bf16x8 (&pb)[2]) {
    const char* Vc = Vbuf[kt % 3];
    bf16x8 vb[4][2];
#pragma unroll
    for (int n = 0; n < 4; n++)
#pragma unroll
      for (int kc = 0; kc < 2; kc++) {
        const int row = n * 16 + fr;
        vb[n][kc] = *(const bf16x8*)(Vc + row * 128 + (((kc << 2) | g) ^ (row & 7)) * 16);
      }
    __builtin_amdgcn_s_setprio(1);
#pragma unroll
    for (int kc = 0; kc < 2; kc++) {
      lacc = __builtin_amdgcn_mfma_f32_16x16x32_bf16(ones, pb[kc], lacc, 0, 0, 0);
#pragma unroll
      for (int n = 0; n < 4; n++)
        o[n] = __builtin_amdgcn_mfma_f32_16x16x32_bf16(vb[n][kc], pb[kc], o[n], 0, 0, 0);
    }
    __builtin_amdgcn_s_setprio(0);
  };

  // ---- prologue: stage tiles 0,1; drain; tile-0 QK+SM ----
  stageKV(0, 0);
  if (ntiles > 1) stageKV(1, 1);
  asm volatile("s_waitcnt vmcnt(0)" ::: "memory");
  __builtin_amdgcn_s_barrier();

  bf16x8 pb[2];
  {
    f32x4 s0[4];
    doQK(0, s0);
    doSM(0, s0, pb);
  }

  for (int t = 0; t < ntiles; t++) {
    if (t + 2 < ntiles) stageKV(t + 2, (t + 2) % 3);

    const bool nxt = (t + 1 < ntiles);
    f32x4 s[4];
    if (nxt) doQK(t + 1, s);          // overlaps PV(t)
    doPV(t, pb);                      // consumes pb(t)
    if (nxt) doSM(t + 1, s, pb);      // rescale o AFTER PV(t); makes pb(t+1)

    if (nxt) {                        // final iteration: no drain, no barrier
      asm volatile("s_waitcnt vmcnt(0)" ::: "memory");
      __builtin_amdgcn_s_barrier();
    }
  }

  // ---- epilogue: O^T -> [q][d] via per-wave LDS region (Kbuf dead) ----
  {
    char* Tw = (char*)Kbuf + w * 2048;           // [16 q][64 d] bf16, psw-swizzled
    const float inv = __builtin_amdgcn_rcpf(lacc[0]);
#pragma unroll
    for (int n = 0; n < 4; n++)
#pragma unroll
      for (int r = 0; r < 4; r++) {
        const int d = n * 16 + g * 4 + r;
        *(__bf16*)(Tw + fr * 128 + ((d * 2) ^ psw(fr))) = (__bf16)(o[n][r] * inv);
      }
#pragma unroll
    for (int i = 0; i < 2; i++) {
      const int c = lane + i * 64;               // 128 16B-chunks
      const int row = c >> 3, pos = c & 7;
      const bf16x8 v = *(const bf16x8*)(Tw + row * 128 + ((pos * 16) ^ psw(row)));
      *(bf16x8*)(yb + (rowbase + q0 + row) * EMB + h * HD + pos * 8) = v;
    }
  }
}

extern "C" void kernel_launch(void* const* d_in, const int* in_sizes, int n_in,
                              void* d_out, int out_size, void* d_ws, size_t ws_size,
                              hipStream_t stream) {
  const float* x     = (const float*)d_in[0];
  const float* w_qkv = (const float*)d_in[1];
  const float* w_out = (const float*)d_in[2];
  float* out = (float*)d_out;

  char* ws = (char*)d_ws;
  __bf16* xb    = (__bf16*)(ws);                 // dead after gemm1 -> reused as yb
  __bf16* wqkvb = (__bf16*)(ws + (8ull  << 20));
  __bf16* wob   = (__bf16*)(ws + (14ull << 20));
  __bf16* qkvb  = (__bf16*)(ws + (16ull << 20));
  __bf16* vtb   = (__bf16*)(ws + (40ull << 20));
  __bf16* yb    = xb;

  cvt_all<<<4096, 256, 0, stream>>>(x, w_qkv, w_out, xb, wqkvb, wob);
  gemm_bt<1><<<dim3(QKVN / 128, NROWS / 128), 256, 0, stream>>>(xb, wqkvb, qkvb, vtb, NROWS, QKVN, EMB);
  attn_causal20<<<1024, 256, 0, stream>>>(qkvb, vtb, yb);
  gemm_bt<0><<<dim3(EMB / 128, NROWS / 128), 256, 0, stream>>>(yb, wob, out, nullptr, NROWS, EMB, EMB);
}